// Round 1
// baseline (651.165 us; speedup 1.0000x reference)
//
#include <hip/hip_runtime.h>
#include <math.h>

// ---------------------------------------------------------------------------
// Problem constants (from reference): B=4096, conv1 (64,5,7) pad3, pool4,
// conv2 (128,64,5) pad2, pool4, fc (404,3072) but only cols 0..5 + tau used.
// Rollout: 100 steps, N=5 basis, DT=0.01, A_X=1, A_Z=25, B_Z=6.25.
// ---------------------------------------------------------------------------

// Kernel 0: tauvec[k] = sum_j L_w[j]*fc_w[j,k]  (k<3072);  taub = L_w·fc_b + L_b
__global__ void precompute_kernel(const float* __restrict__ fc_w,
                                  const float* __restrict__ fc_b,
                                  const float* __restrict__ L_w,
                                  const float* __restrict__ L_b,
                                  float* __restrict__ tauvec,
                                  float* __restrict__ taub) {
    __shared__ float red[4];
    const int t = threadIdx.x;
    if (blockIdx.x < 12) {
        const int k = blockIdx.x * 256 + t;   // 0..3071, coalesced over j rows
        float s = 0.f;
        for (int j = 0; j < 404; ++j) s += L_w[j] * fc_w[j * 3072 + k];
        tauvec[k] = s;
    } else {
        float s = 0.f;
        for (int j = t; j < 404; j += 256) s += L_w[j] * fc_b[j];
        #pragma unroll
        for (int off = 32; off; off >>= 1) s += __shfl_down(s, off);
        if ((t & 63) == 0) red[t >> 6] = s;
        __syncthreads();
        if (t == 0) taub[0] = red[0] + red[1] + red[2] + red[3] + L_b[0];
    }
}

// Kernel 1: per-batch fused conv1+pool -> conv2+pool -> 7-column fc dots
// LDS: reg0 = union{ [in 5x392 | w1 2240 | b1 64], w2-chunk [320][33] } = 10560 f
//      h1   = 64x100 (pad 2 each side)                                  =  6400 f
//      red  = 32 f            total = 67,968 B -> 2 blocks/CU
__global__ __launch_bounds__(256, 2) void fused_kernel(
    const float* __restrict__ input,   // (B,5,384)
    const float* __restrict__ w1,      // (64,5,7)
    const float* __restrict__ b1,      // (64)
    const float* __restrict__ w2,      // (128,64,5)
    const float* __restrict__ b2,      // (128)
    const float* __restrict__ fc_w,    // (404,3072)
    const float* __restrict__ fc_b,    // (404)
    const float* __restrict__ tauvec,  // (3072)
    const float* __restrict__ taubp,   // (1)
    float* __restrict__ params)        // (B,8): goal,w0..w4,tau,pad
{
    __shared__ float reg0[10560];
    __shared__ float h1[6400];
    __shared__ float red[32];
    const int b = blockIdx.x;
    const int t = threadIdx.x;

    float* lds_in = reg0;                 // 5*392
    float* lds_w1 = reg0 + 1960;          // 2240
    float* lds_b1 = reg0 + 4200;          // 64

    // ---- stage input (zero-padded by 3) + conv1 weights ----
    const float* inb = input + (size_t)b * 1920;
    for (int i = t; i < 1920; i += 256) {
        int ic = i / 384, x = i - ic * 384;
        lds_in[ic * 392 + x + 3] = inb[i];
    }
    if (t < 5) {
        lds_in[t*392 + 0] = 0.f; lds_in[t*392 + 1] = 0.f; lds_in[t*392 + 2] = 0.f;
        lds_in[t*392 + 387] = 0.f; lds_in[t*392 + 388] = 0.f; lds_in[t*392 + 389] = 0.f;
    }
    for (int i = t; i < 2240; i += 256) lds_w1[i] = w1[i];
    if (t < 64) {
        lds_b1[t] = b1[t];
        // zero conv2 halo (pad=2 each side) — disjoint from conv1 writes (2..97)
        h1[t*100 + 0] = 0.f; h1[t*100 + 1] = 0.f;
        h1[t*100 + 98] = 0.f; h1[t*100 + 99] = 0.f;
    }
    __syncthreads();

    // ---- conv1 + relu + pool4 -> h1[oc][2+q], q<96 ----
    {
        const int oc = t & 63;
        const int qg = t >> 6;            // 0..3, each thread: 24 q in 4 chunks of 6
        const float bv = lds_b1[oc];
        const float* wrow = lds_w1 + oc * 35;
        for (int c = 0; c < 4; ++c) {
            const int qbase = qg * 24 + c * 6;
            const int pbase = qbase * 4;
            float acc[24];
            #pragma unroll
            for (int p = 0; p < 24; ++p) acc[p] = 0.f;
            for (int ic = 0; ic < 5; ++ic) {
                float v[30];
                const float* src = lds_in + ic * 392 + pbase;   // broadcast across wave
                #pragma unroll
                for (int j = 0; j < 30; ++j) v[j] = src[j];
                #pragma unroll
                for (int k = 0; k < 7; ++k) {
                    const float wv = wrow[ic * 7 + k];
                    #pragma unroll
                    for (int p = 0; p < 24; ++p) acc[p] += wv * v[p + k];
                }
            }
            #pragma unroll
            for (int qq = 0; qq < 6; ++qq) {
                float s = 0.f;
                #pragma unroll
                for (int j = 0; j < 4; ++j) s += fmaxf(acc[qq*4 + j] + bv, 0.f);
                h1[oc * 100 + 2 + qbase + qq] = 0.25f * s;
            }
        }
    }

    // ---- conv2 (4 oc-groups of 32) + relu + pool4, fused 7-col fc dot ----
    float dot[7];
    #pragma unroll
    for (int j = 0; j < 7; ++j) dot[j] = 0.f;
    const int oc_l = t & 31;
    const int qh   = t >> 5;              // 0..7, 3 q each
    for (int g = 0; g < 4; ++g) {
        __syncthreads();                  // conv1 reads / prev-group reads done
        const float* wsrc = w2 + g * 10240;
        for (int i = t; i < 10240; i += 256) {
            int o = i / 320, r = i - o * 320;      // global read coalesced
            reg0[r * 33 + o] = wsrc[i];            // LDS write stride 33: conflict-free
        }
        __syncthreads();
        const int oc = g * 32 + oc_l;
        const float b2v = b2[oc];
        float acc[12];
        #pragma unroll
        for (int p = 0; p < 12; ++p) acc[p] = 0.f;
        for (int ic = 0; ic < 64; ++ic) {
            float v[16];
            const float* src = h1 + ic * 100 + qh * 12;
            #pragma unroll
            for (int j = 0; j < 16; ++j) v[j] = src[j];
            #pragma unroll
            for (int k = 0; k < 5; ++k) {
                const float wv = reg0[(ic * 5 + k) * 33 + oc_l];  // stride-1 over lanes
                #pragma unroll
                for (int p = 0; p < 12; ++p) acc[p] += wv * v[p + k];
            }
        }
        #pragma unroll
        for (int qq = 0; qq < 3; ++qq) {
            float s = 0.f;
            #pragma unroll
            for (int j = 0; j < 4; ++j) s += fmaxf(acc[qq*4 + j] + b2v, 0.f);
            const float feat = 0.25f * s;
            const int idx = oc * 24 + qh * 3 + qq;
            #pragma unroll
            for (int j = 0; j < 6; ++j) dot[j] += feat * fc_w[j * 3072 + idx];
            dot[6] += feat * tauvec[idx];
        }
    }

    // ---- block-reduce the 7 dots ----
    #pragma unroll
    for (int j = 0; j < 7; ++j) {
        float s = dot[j];
        #pragma unroll
        for (int off = 32; off; off >>= 1) s += __shfl_down(s, off);
        dot[j] = s;
    }
    if ((t & 63) == 0) {
        const int wv = t >> 6;
        #pragma unroll
        for (int j = 0; j < 7; ++j) red[wv * 8 + j] = dot[j];
    }
    __syncthreads();
    if (t < 7) {
        float s = red[t] + red[8 + t] + red[16 + t] + red[24 + t];
        s += (t < 6) ? fc_b[t] : taubp[0];
        params[(size_t)b * 8 + t] = s;
    }
}

// Kernel 2: DMP rollout — 1 thread per batch element, 100 sequential steps.
__global__ void rollout_kernel(const float* __restrict__ params,
                               const float* __restrict__ y0,
                               float* __restrict__ out) {
    const int b = blockIdx.x * 256 + threadIdx.x;
    const float* p = params + (size_t)b * 8;
    const float goal = p[0];
    const float w0 = p[1], w1 = p[2], w2 = p[3], w3 = p[4], w4 = p[5];
    const float tau = p[6];
    const float y0v = y0[b];

    // _C = exp(-linspace(0,1,5)); _SIGMA2 = 5^1.5 / _C
    const float c0 = 1.0f;
    const float c1 = 0.77880078307140486825f;   // exp(-0.25)
    const float c2 = 0.60653065971263342360f;   // exp(-0.5)
    const float c3 = 0.47236655274101470714f;   // exp(-0.75)
    const float c4 = 0.36787944117144232160f;   // exp(-1)
    const float inv2s = -0.5f / 11.180339887498949f;  // -0.5/N^1.5, times c_i below
    const float e0 = inv2s * c0, e1 = inv2s * c1, e2 = inv2s * c2,
                e3 = inv2s * c3, e4 = inv2s * c4;

    float x = 1.0f, y = y0v, z = 0.01f * tau;
    const float td = tau * 0.01f;           // tau*DT
    const float gmy0 = goal - y0v;
    float* ob = out + (size_t)b * 101;
    ob[0] = y0v;
    for (int s = 1; s <= 100; ++s) {
        x = x - x * td;
        const float d0 = x - c0, d1 = x - c1, d2 = x - c2, d3 = x - c3, d4 = x - c4;
        const float p0 = __expf(e0 * d0 * d0);
        const float p1 = __expf(e1 * d1 * d1);
        const float p2 = __expf(e2 * d2 * d2);
        const float p3 = __expf(e3 * d3 * d3);
        const float p4 = __expf(e4 * d4 * d4);
        const float den = p0 + p1 + p2 + p3 + p4;
        const float num = w0*p0 + w1*p1 + w2*p2 + w3*p3 + w4*p4;
        const float fx = (num / den) * x * gmy0;
        const float dz = 25.0f * (6.25f * (goal - y) - z) + fx;
        const float dy = z;
        y += dy * td;
        z += dz * td;
        ob[s] = y;
    }
}

extern "C" void kernel_launch(void* const* d_in, const int* in_sizes, int n_in,
                              void* d_out, int out_size, void* d_ws, size_t ws_size,
                              hipStream_t stream) {
    const float* input = (const float*)d_in[0];
    const float* y0    = (const float*)d_in[1];
    const float* w1    = (const float*)d_in[2];
    const float* b1    = (const float*)d_in[3];
    const float* w2    = (const float*)d_in[4];
    const float* b2    = (const float*)d_in[5];
    const float* fc_w  = (const float*)d_in[6];
    const float* fc_b  = (const float*)d_in[7];
    const float* L_w   = (const float*)d_in[8];
    const float* L_b   = (const float*)d_in[9];
    float* out = (float*)d_out;

    float* ws     = (float*)d_ws;
    float* tauvec = ws;            // 3072
    float* taub   = ws + 3072;     // 1 (padded to 3080)
    float* params = ws + 3080;     // B*8

    const int B = in_sizes[1];     // 4096

    precompute_kernel<<<13, 256, 0, stream>>>(fc_w, fc_b, L_w, L_b, tauvec, taub);
    fused_kernel<<<B, 256, 0, stream>>>(input, w1, b1, w2, b2, fc_w, fc_b,
                                        tauvec, taub, params);
    rollout_kernel<<<B / 256, 256, 0, stream>>>(params, y0, out);
}

// Round 2
// 209.099 us; speedup vs baseline: 3.1141x; 3.1141x over previous
//
#include <hip/hip_runtime.h>
#include <math.h>

// ---------------------------------------------------------------------------
// B=4096. conv1 (64,5,7) pad3 + relu + pool4 -> h1 (64,96)
//         conv2 (128,64,5) pad2 + relu + pool4 -> feat (128,24)
//         fc: only cols 0..5 of (404,3072) + tau = feat·(L_w@fc_w) + const.
// Rollout: 100 steps, N=5 basis, DT=0.01.
// Convs run as split-bf16 MFMA GEMMs (hi+lo, 3 mfma/product, err ~2^-18/term):
//   conv1: C[pos=384][oc=64],  K'=64  (k' = dk*8+ic, zero-padded)
//   conv2: C[pos=96][oc=128],  K=320  (k' = dk*64+ic, dk-major so A-frag
//          reads are constant-stride LDS with immediate offsets)
// C/D layout (m89): col=lane&15 -> oc, row=(lane>>4)*4+reg -> pos, so the
// 4-to-1 pos pooling is an in-register 4-term sum.
// ---------------------------------------------------------------------------

typedef short bf16x8 __attribute__((ext_vector_type(8)));
typedef float f32x4  __attribute__((ext_vector_type(4)));
typedef int   i32x4  __attribute__((ext_vector_type(4)));

union Frag { int u[4]; i32x4 q; bf16x8 v; };

__device__ __forceinline__ unsigned bf16_rne(float f) {
    unsigned u = __float_as_uint(f);
    return (u + 0x7fffu + ((u >> 16) & 1u)) >> 16;
}
// pack (hi bf16 << 16) | lo bf16, where hi = rne(f), lo = rne(f - hi)
__device__ __forceinline__ unsigned packsplit(float f) {
    unsigned hi = bf16_rne(f);
    float lo = f - __uint_as_float(hi << 16);   // exact (Sterbenz-ish)
    return (hi << 16) | bf16_rne(lo);
}

// ---------------------------------------------------------------------------
// Kernel 0: fc7 table, taub, and MFMA-fragment-layout weight tables (hi/lo).
//   fc7[k][0..5] = fc_w[j][k], fc7[k][6] = (L_w @ fc_w)[k], fc7[k][7]=0
//   wfrag1: [split2][ks2][oct4][lane64][4 u32]   (conv1, K'=64, zero-padded)
//   wfrag2: [split2][ks10][oct8][lane64][4 u32]  (conv2, K=320, dk-major)
// ---------------------------------------------------------------------------
__global__ void precompute_kernel(const float* __restrict__ w1,
                                  const float* __restrict__ w2,
                                  const float* __restrict__ fc_w,
                                  const float* __restrict__ fc_b,
                                  const float* __restrict__ L_w,
                                  const float* __restrict__ L_b,
                                  float* __restrict__ fc7,
                                  float* __restrict__ taub,
                                  unsigned* __restrict__ wfrag1,
                                  unsigned* __restrict__ wfrag2) {
    const int t = threadIdx.x, bb = blockIdx.x;
    if (bb < 12) {
        const int k = bb * 256 + t;                 // 0..3071
        float tv = 0.f;
        for (int j = 0; j < 404; ++j) tv += L_w[j] * fc_w[j * 3072 + k];
        float r[8];
        #pragma unroll
        for (int j = 0; j < 6; ++j) r[j] = fc_w[j * 3072 + k];
        r[6] = tv; r[7] = 0.f;
        #pragma unroll
        for (int j = 0; j < 8; ++j) fc7[k * 8 + j] = r[j];
    } else if (bb == 12) {
        if (t < 64) {
            float s = 0.f;
            for (int j = t; j < 404; j += 64) s += L_w[j] * fc_b[j];
            #pragma unroll
            for (int off = 32; off; off >>= 1) s += __shfl_down(s, off);
            if (t == 0) taub[0] = s + L_b[0];
        }
        for (int it = t; it < 1024; it += 256) {    // conv1 frags
            const int split = it >> 9, ks = (it >> 8) & 1,
                      oct = (it >> 6) & 3, lane = it & 63;
            const int oc = oct * 16 + (lane & 15);
            unsigned h[8];
            #pragma unroll
            for (int j = 0; j < 8; ++j) {
                const int kp = ks * 32 + (lane >> 4) * 8 + j;  // k' = dk*8+ic
                const int dk = kp >> 3, ic = kp & 7;
                float v = (ic < 5 && dk < 7) ? w1[oc * 35 + ic * 7 + dk] : 0.f;
                unsigned hb = bf16_rne(v);
                if (split) hb = bf16_rne(v - __uint_as_float(hb << 16));
                h[j] = hb;
            }
            #pragma unroll
            for (int wj = 0; wj < 4; ++wj)
                wfrag1[it * 4 + wj] = (h[2 * wj + 1] << 16) | h[2 * wj];
        }
    } else {                                        // conv2 frags: 10240 items
        const int base = (bb - 13) * 512;
        #pragma unroll
        for (int r = 0; r < 2; ++r) {
            const int it = base + r * 256 + t;
            const int split = it / 5120, rem = it % 5120;
            const int ks = rem >> 9, oct = (rem >> 6) & 7, lane = rem & 63;
            const int oc = oct * 16 + (lane & 15);
            unsigned h[8];
            #pragma unroll
            for (int j = 0; j < 8; ++j) {
                const int kp = ks * 32 + (lane >> 4) * 8 + j;  // k' = dk*64+ic
                const int dk = kp >> 6, ic = kp & 63;
                const float v = w2[oc * 320 + ic * 5 + dk];
                unsigned hb = bf16_rne(v);
                if (split) hb = bf16_rne(v - __uint_as_float(hb << 16));
                h[j] = hb;
            }
            #pragma unroll
            for (int wj = 0; wj < 4; ++wj)
                wfrag2[it * 4 + wj] = (h[2 * wj + 1] << 16) | h[2 * wj];
        }
    }
}

// ---------------------------------------------------------------------------
// Kernel 1: per-batch fused conv1+conv2 (split-bf16 MFMA) + 7-col fc dots.
// LDS: lds_in u32[8][392] packed hi|lo (rows 5..7 + halos zero) = 12.5 KB
//      h1p    u32[64][101] packed hi|lo (halo c=0,1,98,99 zero)  = 25.9 KB
// ---------------------------------------------------------------------------
__global__ __launch_bounds__(256, 2) void fused_kernel(
    const float* __restrict__ input,     // (B,5,384)
    const float* __restrict__ b1,        // (64)
    const float* __restrict__ b2,        // (128)
    const unsigned* __restrict__ wfrag1,
    const unsigned* __restrict__ wfrag2,
    const float* __restrict__ fc7,       // (3072,8)
    const float* __restrict__ fc_b,      // (404)
    const float* __restrict__ taubp,     // (1)
    float* __restrict__ params)          // (B,8)
{
    __shared__ unsigned lds_in[8 * 392];
    __shared__ unsigned h1p[64 * 101];
    __shared__ float red[32];
    const int t = threadIdx.x, b = blockIdx.x;
    const int lane = t & 63, w = t >> 6;
    const int lg = lane >> 4, lr = lane & 15;

    // ---- stage: zero-everything, then fill input as packed hi|lo bf16 ----
    for (int i = t; i < 3136; i += 256) lds_in[i] = 0u;
    { const int ic = t >> 2, cc = t & 3;
      h1p[ic * 101 + ((cc < 2) ? cc : 96 + cc)] = 0u; }   // conv2 halo
    __syncthreads();
    const float* inb = input + (size_t)b * 1920;
    for (int i = t; i < 1920; i += 256) {
        const int ic = i / 384, x = i - ic * 384;
        lds_in[ic * 392 + 3 + x] = packsplit(inb[i]);
    }
    __syncthreads();

    // ---------------- conv1: C[pos=384][oc=64], K'=64 ----------------
    f32x4 acc1[6][4];
    #pragma unroll
    for (int mt = 0; mt < 6; ++mt)
        #pragma unroll
        for (int oct = 0; oct < 4; ++oct) acc1[mt][oct] = (f32x4){0.f, 0.f, 0.f, 0.f};

    const unsigned* aB1 = lds_in + w * 96 + lr + lg;   // + mt*16 + ks*4 + j*392
    const i32x4* w1f = (const i32x4*)wfrag1;
    #pragma unroll
    for (int ks = 0; ks < 2; ++ks) {
        Frag bh[4], bl[4];
        #pragma unroll
        for (int oct = 0; oct < 4; ++oct) {
            bh[oct].q = w1f[(ks * 4 + oct) * 64 + lane];
            bl[oct].q = w1f[((2 + ks) * 4 + oct) * 64 + lane];
        }
        #pragma unroll
        for (int mt = 0; mt < 6; ++mt) {
            unsigned p[8];
            #pragma unroll
            for (int j = 0; j < 8; ++j) p[j] = aB1[mt * 16 + ks * 4 + j * 392];
            Frag ah, al;
            #pragma unroll
            for (int wj = 0; wj < 4; ++wj) {
                ah.u[wj] = __builtin_amdgcn_perm(p[2*wj+1], p[2*wj], 0x07060302u);
                al.u[wj] = __builtin_amdgcn_perm(p[2*wj+1], p[2*wj], 0x05040100u);
            }
            #pragma unroll
            for (int oct = 0; oct < 4; ++oct) {
                acc1[mt][oct] = __builtin_amdgcn_mfma_f32_16x16x32_bf16(ah.v, bh[oct].v, acc1[mt][oct], 0, 0, 0);
                acc1[mt][oct] = __builtin_amdgcn_mfma_f32_16x16x32_bf16(ah.v, bl[oct].v, acc1[mt][oct], 0, 0, 0);
                acc1[mt][oct] = __builtin_amdgcn_mfma_f32_16x16x32_bf16(al.v, bh[oct].v, acc1[mt][oct], 0, 0, 0);
            }
        }
    }
    // epilogue: bias + relu + pool4 (in-register rows) -> h1p packed
    {
        float b1v[4];
        #pragma unroll
        for (int oct = 0; oct < 4; ++oct) b1v[oct] = b1[oct * 16 + lr];
        #pragma unroll
        for (int mt = 0; mt < 6; ++mt) {
            const int q = (w * 6 + mt) * 4 + lg;
            #pragma unroll
            for (int oct = 0; oct < 4; ++oct) {
                float s = 0.f;
                #pragma unroll
                for (int r4 = 0; r4 < 4; ++r4)
                    s += fmaxf(acc1[mt][oct][r4] + b1v[oct], 0.f);
                h1p[(oct * 16 + lr) * 101 + 2 + q] = packsplit(0.25f * s);
            }
        }
    }
    __syncthreads();

    // ---------------- conv2: C[pos=96][oc=128], K=320 ----------------
    f32x4 acc2[3][4];
    #pragma unroll
    for (int mt = 0; mt < 3; ++mt)
        #pragma unroll
        for (int oct = 0; oct < 4; ++oct) acc2[mt][oct] = (f32x4){0.f, 0.f, 0.f, 0.f};

    const int mbase = (w & 1) * 3, nbase = (w >> 1) * 4;
    // word addr = (lg*8 + (ks&1)*32 + j)*101 + (mbase+mt)*16 + lr + (ks>>1)
    const unsigned* aB2 = h1p + lg * 808 + mbase * 16 + lr;
    const i32x4* w2f = (const i32x4*)wfrag2;
    #pragma unroll
    for (int ks = 0; ks < 10; ++ks) {
        Frag bh[4], bl[4];
        #pragma unroll
        for (int oct = 0; oct < 4; ++oct) {
            bh[oct].q = w2f[(ks * 8 + nbase + oct) * 64 + lane];
            bl[oct].q = w2f[((10 + ks) * 8 + nbase + oct) * 64 + lane];
        }
        #pragma unroll
        for (int mt = 0; mt < 3; ++mt) {
            unsigned p[8];
            #pragma unroll
            for (int j = 0; j < 8; ++j)
                p[j] = aB2[(ks & 1) * 3232 + (ks >> 1) + mt * 16 + j * 101];
            Frag ah, al;
            #pragma unroll
            for (int wj = 0; wj < 4; ++wj) {
                ah.u[wj] = __builtin_amdgcn_perm(p[2*wj+1], p[2*wj], 0x07060302u);
                al.u[wj] = __builtin_amdgcn_perm(p[2*wj+1], p[2*wj], 0x05040100u);
            }
            #pragma unroll
            for (int oct = 0; oct < 4; ++oct) {
                acc2[mt][oct] = __builtin_amdgcn_mfma_f32_16x16x32_bf16(ah.v, bh[oct].v, acc2[mt][oct], 0, 0, 0);
                acc2[mt][oct] = __builtin_amdgcn_mfma_f32_16x16x32_bf16(ah.v, bl[oct].v, acc2[mt][oct], 0, 0, 0);
                acc2[mt][oct] = __builtin_amdgcn_mfma_f32_16x16x32_bf16(al.v, bh[oct].v, acc2[mt][oct], 0, 0, 0);
            }
        }
    }

    // epilogue: bias+relu+pool4 -> feat; fused 7-col fc dot via fc7 table
    float dot[7] = {0.f, 0.f, 0.f, 0.f, 0.f, 0.f, 0.f};
    {
        float b2v[4];
        #pragma unroll
        for (int oct = 0; oct < 4; ++oct) b2v[oct] = b2[(nbase + oct) * 16 + lr];
        #pragma unroll
        for (int mt = 0; mt < 3; ++mt) {
            const int q = (mbase + mt) * 4 + lg;
            #pragma unroll
            for (int oct = 0; oct < 4; ++oct) {
                float s = 0.f;
                #pragma unroll
                for (int r4 = 0; r4 < 4; ++r4)
                    s += fmaxf(acc2[mt][oct][r4] + b2v[oct], 0.f);
                s *= 0.25f;
                const int idx = ((nbase + oct) * 16 + lr) * 24 + q;
                const f32x4* fp = (const f32x4*)(fc7 + idx * 8);
                const f32x4 f0 = fp[0], f1 = fp[1];
                dot[0] += s * f0[0]; dot[1] += s * f0[1];
                dot[2] += s * f0[2]; dot[3] += s * f0[3];
                dot[4] += s * f1[0]; dot[5] += s * f1[1];
                dot[6] += s * f1[2];
            }
        }
    }

    // ---- block-reduce 7 dots ----
    #pragma unroll
    for (int j = 0; j < 7; ++j) {
        float s = dot[j];
        #pragma unroll
        for (int off = 32; off; off >>= 1) s += __shfl_down(s, off);
        if (lane == 0) red[w * 8 + j] = s;
    }
    __syncthreads();
    if (t < 7) {
        float s = red[t] + red[8 + t] + red[16 + t] + red[24 + t];
        s += (t < 6) ? fc_b[t] : taubp[0];
        params[(size_t)b * 8 + t] = s;
    }
}

// ---------------------------------------------------------------------------
// Kernel 2: DMP rollout — 1 thread per batch element, 100 sequential steps.
// ---------------------------------------------------------------------------
__global__ void rollout_kernel(const float* __restrict__ params,
                               const float* __restrict__ y0,
                               float* __restrict__ out) {
    const int b = blockIdx.x * 256 + threadIdx.x;
    const float* p = params + (size_t)b * 8;
    const float goal = p[0];
    const float w0 = p[1], w1 = p[2], w2 = p[3], w3 = p[4], w4 = p[5];
    const float tau = p[6];
    const float y0v = y0[b];

    const float c0 = 1.0f;
    const float c1 = 0.77880078307140486825f;
    const float c2 = 0.60653065971263342360f;
    const float c3 = 0.47236655274101470714f;
    const float c4 = 0.36787944117144232160f;
    const float inv2s = -0.5f / 11.180339887498949f;
    const float e0 = inv2s * c0, e1 = inv2s * c1, e2 = inv2s * c2,
                e3 = inv2s * c3, e4 = inv2s * c4;

    float x = 1.0f, y = y0v, z = 0.01f * tau;
    const float td = tau * 0.01f;
    const float gmy0 = goal - y0v;
    float* ob = out + (size_t)b * 101;
    ob[0] = y0v;
    for (int s = 1; s <= 100; ++s) {
        x = x - x * td;
        const float d0 = x - c0, d1 = x - c1, d2 = x - c2, d3 = x - c3, d4 = x - c4;
        const float p0 = __expf(e0 * d0 * d0);
        const float p1 = __expf(e1 * d1 * d1);
        const float p2 = __expf(e2 * d2 * d2);
        const float p3 = __expf(e3 * d3 * d3);
        const float p4 = __expf(e4 * d4 * d4);
        const float den = p0 + p1 + p2 + p3 + p4;
        const float num = w0 * p0 + w1 * p1 + w2 * p2 + w3 * p3 + w4 * p4;
        const float fx = (num / den) * x * gmy0;
        const float dz = 25.0f * (6.25f * (goal - y) - z) + fx;
        const float dy = z;
        y += dy * td;
        z += dz * td;
        ob[s] = y;
    }
}

extern "C" void kernel_launch(void* const* d_in, const int* in_sizes, int n_in,
                              void* d_out, int out_size, void* d_ws, size_t ws_size,
                              hipStream_t stream) {
    const float* input = (const float*)d_in[0];
    const float* y0    = (const float*)d_in[1];
    const float* w1    = (const float*)d_in[2];
    const float* b1    = (const float*)d_in[3];
    const float* w2    = (const float*)d_in[4];
    const float* b2    = (const float*)d_in[5];
    const float* fc_w  = (const float*)d_in[6];
    const float* fc_b  = (const float*)d_in[7];
    const float* L_w   = (const float*)d_in[8];
    const float* L_b   = (const float*)d_in[9];
    float* out = (float*)d_out;

    float* ws      = (float*)d_ws;
    float* fc7     = ws;                       // 3072*8 = 24576 f
    float* taub    = ws + 24576;               // 1 (padded to 64)
    float* params  = ws + 24640;               // 4096*8 = 32768 f
    unsigned* wfrag1 = (unsigned*)(ws + 57408);   // 4096 u32 (16 KB)
    unsigned* wfrag2 = wfrag1 + 4096;             // 40960 u32 (160 KB)

    const int B = in_sizes[1];                 // 4096

    precompute_kernel<<<33, 256, 0, stream>>>(w1, w2, fc_w, fc_b, L_w, L_b,
                                              fc7, taub, wfrag1, wfrag2);
    fused_kernel<<<B, 256, 0, stream>>>(input, b1, b2, wfrag1, wfrag2,
                                        fc7, fc_b, taub, params);
    rollout_kernel<<<B / 256, 256, 0, stream>>>(params, y0, out);
}

// Round 3
// 180.678 us; speedup vs baseline: 3.6040x; 1.1573x over previous
//
#include <hip/hip_runtime.h>
#include <math.h>

// ---------------------------------------------------------------------------
// B=4096. conv1 (64,5,7) pad3 + relu + pool4 -> h1 (64,96)
//         conv2 (128,64,5) pad2 + relu + pool4 -> feat (128,24)
//         fc: only cols 0..5 of (404,3072) + tau = feat·(L_w@fc_w) + const.
// Split-bf16 MFMA (hi+lo, 3 mfma/product). conv2 = 5 shifted GEMMs (tap dk)
// over K=64(ic), A-frags read as ds_read_b128 from transposed h1t hi/lo.
// C/D layout (m89): col=lane&15 -> oc, row=(lane>>4)*4+reg -> pos (pool4 is
// an in-register 4-term sum).
// ---------------------------------------------------------------------------

typedef short bf16x8 __attribute__((ext_vector_type(8)));
typedef float f32x4  __attribute__((ext_vector_type(4)));
typedef int   i32x4  __attribute__((ext_vector_type(4)));

union Frag { int u[4]; i32x4 q; bf16x8 v; };

__device__ __forceinline__ unsigned bf16_rne(float f) {
    unsigned u = __float_as_uint(f);
    return (u + 0x7fffu + ((u >> 16) & 1u)) >> 16;
}
__device__ __forceinline__ unsigned packsplit(float f) {
    unsigned hi = bf16_rne(f);
    float lo = f - __uint_as_float(hi << 16);
    return (hi << 16) | bf16_rne(lo);
}

// ---------------------------------------------------------------------------
// Kernel 0: fc7 table, taub, weight-fragment tables (hi/lo).
//  wfrag1: [split2][ks2][oct4][lane64][4u32]          (conv1, K'=64 padded)
//  wfrag2: [split2][dk5][ks2][oct8][lane64][4u32]     (conv2 taps, K=64=ic)
// ---------------------------------------------------------------------------
__global__ void precompute_kernel(const float* __restrict__ w1,
                                  const float* __restrict__ w2,
                                  const float* __restrict__ fc_w,
                                  const float* __restrict__ fc_b,
                                  const float* __restrict__ L_w,
                                  const float* __restrict__ L_b,
                                  float* __restrict__ fc7,
                                  float* __restrict__ taub,
                                  unsigned* __restrict__ wfrag1,
                                  unsigned* __restrict__ wfrag2) {
    const int t = threadIdx.x, bb = blockIdx.x;
    if (bb < 12) {
        const int k = bb * 256 + t;
        float tv = 0.f;
        for (int j = 0; j < 404; ++j) tv += L_w[j] * fc_w[j * 3072 + k];
        float r[8];
        #pragma unroll
        for (int j = 0; j < 6; ++j) r[j] = fc_w[j * 3072 + k];
        r[6] = tv; r[7] = 0.f;
        #pragma unroll
        for (int j = 0; j < 8; ++j) fc7[k * 8 + j] = r[j];
    } else if (bb == 12) {
        if (t < 64) {
            float s = 0.f;
            for (int j = t; j < 404; j += 64) s += L_w[j] * fc_b[j];
            #pragma unroll
            for (int off = 32; off; off >>= 1) s += __shfl_down(s, off);
            if (t == 0) taub[0] = s + L_b[0];
        }
        for (int it = t; it < 1024; it += 256) {    // conv1 frags
            const int split = it >> 9, ks = (it >> 8) & 1,
                      oct = (it >> 6) & 3, lane = it & 63;
            const int oc = oct * 16 + (lane & 15);
            unsigned h[8];
            #pragma unroll
            for (int j = 0; j < 8; ++j) {
                const int kp = ks * 32 + (lane >> 4) * 8 + j;  // k' = dk*8+ic
                const int dk = kp >> 3, ic = kp & 7;
                float v = (ic < 5 && dk < 7) ? w1[oc * 35 + ic * 7 + dk] : 0.f;
                unsigned hb = bf16_rne(v);
                if (split) hb = bf16_rne(v - __uint_as_float(hb << 16));
                h[j] = hb;
            }
            #pragma unroll
            for (int wj = 0; wj < 4; ++wj)
                wfrag1[it * 4 + wj] = (h[2 * wj + 1] << 16) | h[2 * wj];
        }
    } else {                                        // conv2 tap frags: 10240
        const int base = (bb - 13) * 512;
        #pragma unroll
        for (int r = 0; r < 2; ++r) {
            const int it = base + r * 256 + t;
            const int split = it / 5120, rem = it % 5120;
            const int dk = rem >> 10, rem2 = rem & 1023;
            const int ks = rem2 >> 9, oct = (rem2 >> 6) & 7, lane = rem2 & 63;
            const int oc = oct * 16 + (lane & 15);
            unsigned h[8];
            #pragma unroll
            for (int j = 0; j < 8; ++j) {
                const int ic = ks * 32 + (lane >> 4) * 8 + j;   // k = ic
                const float v = w2[oc * 320 + ic * 5 + dk];
                unsigned hb = bf16_rne(v);
                if (split) hb = bf16_rne(v - __uint_as_float(hb << 16));
                h[j] = hb;
            }
            #pragma unroll
            for (int wj = 0; wj < 4; ++wj)
                wfrag2[it * 4 + wj] = (h[2 * wj + 1] << 16) | h[2 * wj];
        }
    }
}

// ---------------------------------------------------------------------------
// Kernel 1: fused conv1 + conv2 + 7-col fc.  LDS layout (38336 B):
//  [0,9408)      lds_in  u32[6][392]  packed hi|lo (row5 = zeros)
//  [9408,23808)  h1t_hi  bf16[100][72] (rows 0,1,98,99 halo-zero, cols<64)
//  [23808,38208) h1t_lo  bf16[100][72]
//  [38208,38336) red     f32[32]
// ---------------------------------------------------------------------------
__global__ __launch_bounds__(256, 3) void fused_kernel(
    const float* __restrict__ input,
    const float* __restrict__ b1,
    const float* __restrict__ b2,
    const unsigned* __restrict__ wfrag1,
    const unsigned* __restrict__ wfrag2,
    const float* __restrict__ fc7,
    const float* __restrict__ fc_b,
    const float* __restrict__ taubp,
    float* __restrict__ params)
{
    __shared__ __align__(16) unsigned char smem[38336];
    unsigned* lds_in = (unsigned*)smem;                  // 2352 u32
    unsigned short* h1t_hi = (unsigned short*)(smem + 9408);
    unsigned short* h1t_lo = (unsigned short*)(smem + 23808);
    unsigned* h1t_hi32 = (unsigned*)(smem + 9408);
    unsigned* h1t_lo32 = (unsigned*)(smem + 23808);
    float* red = (float*)(smem + 38208);

    const int t = threadIdx.x, b = blockIdx.x;
    const int lane = t & 63, w = t >> 6;
    const int lg = lane >> 4, lr = lane & 15;

    // ---- stage: zero lds_in + h1t halo rows, then fill packed input ----
    for (int i = t; i < 2352; i += 256) lds_in[i] = 0u;
    {   // rows {0,1,98,99} x words 0..31 x {hi,lo}
        const int arr = t >> 7, rs = (t >> 5) & 3, word = t & 31;
        const int row = (rs < 2) ? rs : 96 + rs;
        (arr ? h1t_lo32 : h1t_hi32)[row * 36 + word] = 0u;
    }
    __syncthreads();
    const float* inb = input + (size_t)b * 1920;
    for (int i = t; i < 1920; i += 256) {
        const int ic = i / 384, x = i - ic * 384;
        lds_in[ic * 392 + 3 + x] = packsplit(inb[i]);
    }
    __syncthreads();

    // ---------------- conv1: C[pos=384][oc=64], K'=64 ----------------
    const i32x4* w1f = (const i32x4*)wfrag1;
    Frag c1bh[2][4], c1bl[2][4];
    #pragma unroll
    for (int ks = 0; ks < 2; ++ks)
        #pragma unroll
        for (int oct = 0; oct < 4; ++oct) {
            c1bh[ks][oct].q = w1f[(ks * 4 + oct) * 64 + lane];
            c1bl[ks][oct].q = w1f[((2 + ks) * 4 + oct) * 64 + lane];
        }
    float b1v[4];
    #pragma unroll
    for (int oct = 0; oct < 4; ++oct) b1v[oct] = b1[oct * 16 + lr];

    float pooled[6][4];
    const unsigned* aB1 = lds_in + w * 96 + lr + lg;
    #pragma unroll
    for (int mt = 0; mt < 6; ++mt) {
        f32x4 acc[4];
        #pragma unroll
        for (int oct = 0; oct < 4; ++oct) acc[oct] = (f32x4){0.f, 0.f, 0.f, 0.f};
        #pragma unroll
        for (int ks = 0; ks < 2; ++ks) {
            unsigned p[8];
            #pragma unroll
            for (int j = 0; j < 8; ++j) {
                const int jr = (j < 5) ? j : 5;          // rows 5..7 are zero row
                p[j] = aB1[mt * 16 + ks * 4 + jr * 392];
            }
            Frag ah, al;
            #pragma unroll
            for (int wj = 0; wj < 4; ++wj) {
                ah.u[wj] = __builtin_amdgcn_perm(p[2*wj+1], p[2*wj], 0x07060302u);
                al.u[wj] = __builtin_amdgcn_perm(p[2*wj+1], p[2*wj], 0x05040100u);
            }
            #pragma unroll
            for (int oct = 0; oct < 4; ++oct)
                acc[oct] = __builtin_amdgcn_mfma_f32_16x16x32_bf16(ah.v, c1bh[ks][oct].v, acc[oct], 0, 0, 0);
            #pragma unroll
            for (int oct = 0; oct < 4; ++oct)
                acc[oct] = __builtin_amdgcn_mfma_f32_16x16x32_bf16(ah.v, c1bl[ks][oct].v, acc[oct], 0, 0, 0);
            #pragma unroll
            for (int oct = 0; oct < 4; ++oct)
                acc[oct] = __builtin_amdgcn_mfma_f32_16x16x32_bf16(al.v, c1bh[ks][oct].v, acc[oct], 0, 0, 0);
        }
        #pragma unroll
        for (int oct = 0; oct < 4; ++oct) {
            float s = 0.f;
            #pragma unroll
            for (int r4 = 0; r4 < 4; ++r4) s += fmaxf(acc[oct][r4] + b1v[oct], 0.f);
            pooled[mt][oct] = 0.25f * s;
        }
    }
    // transposed split write: h1t[c+2][oc]
    #pragma unroll
    for (int mt = 0; mt < 6; ++mt) {
        const int c = (w * 6 + mt) * 4 + lg;
        #pragma unroll
        for (int oct = 0; oct < 4; ++oct) {
            const float v = pooled[mt][oct];
            const unsigned hi = bf16_rne(v);
            const unsigned lo = bf16_rne(v - __uint_as_float(hi << 16));
            const int idx = (c + 2) * 72 + oct * 16 + lr;
            h1t_hi[idx] = (unsigned short)hi;
            h1t_lo[idx] = (unsigned short)lo;
        }
    }
    __syncthreads();

    // -------- conv2: 5 taps x K=64, C[pos=96][oc=128] --------
    const int mbase = (w & 1) * 3, nbase = (w >> 1) * 4;
    f32x4 acc2[3][4];
    #pragma unroll
    for (int mt = 0; mt < 3; ++mt)
        #pragma unroll
        for (int oct = 0; oct < 4; ++oct) acc2[mt][oct] = (f32x4){0.f, 0.f, 0.f, 0.f};

    // A base: ((mbase*16+lr)*72 + lg*8) bf16; elem-16B offsets: mt*144+dk*9+ks*4
    const i32x4* aHi = (const i32x4*)(h1t_hi + ((mbase * 16 + lr) * 72 + lg * 8));
    const i32x4* aLo = (const i32x4*)(h1t_lo + ((mbase * 16 + lr) * 72 + lg * 8));
    const i32x4* w2f = (const i32x4*)wfrag2;
    #pragma unroll
    for (int dk = 0; dk < 5; ++dk) {
        #pragma unroll
        for (int ks = 0; ks < 2; ++ks) {
            Frag bh[4], bl[4];
            #pragma unroll
            for (int oct = 0; oct < 4; ++oct) {
                bh[oct].q = w2f[((dk * 2 + ks) * 8 + nbase + oct) * 64 + lane];
                bl[oct].q = w2f[(((5 + dk) * 2 + ks) * 8 + nbase + oct) * 64 + lane];
            }
            #pragma unroll
            for (int mt = 0; mt < 3; ++mt) {
                Frag ah, al;
                ah.q = aHi[mt * 144 + dk * 9 + ks * 4];
                al.q = aLo[mt * 144 + dk * 9 + ks * 4];
                #pragma unroll
                for (int oct = 0; oct < 4; ++oct)
                    acc2[mt][oct] = __builtin_amdgcn_mfma_f32_16x16x32_bf16(ah.v, bh[oct].v, acc2[mt][oct], 0, 0, 0);
                #pragma unroll
                for (int oct = 0; oct < 4; ++oct)
                    acc2[mt][oct] = __builtin_amdgcn_mfma_f32_16x16x32_bf16(ah.v, bl[oct].v, acc2[mt][oct], 0, 0, 0);
                #pragma unroll
                for (int oct = 0; oct < 4; ++oct)
                    acc2[mt][oct] = __builtin_amdgcn_mfma_f32_16x16x32_bf16(al.v, bh[oct].v, acc2[mt][oct], 0, 0, 0);
            }
        }
    }

    // epilogue: bias+relu+pool4 -> feat; fused 7-col fc dot via fc7 table
    float dot[7] = {0.f, 0.f, 0.f, 0.f, 0.f, 0.f, 0.f};
    {
        float b2v[4];
        #pragma unroll
        for (int oct = 0; oct < 4; ++oct) b2v[oct] = b2[(nbase + oct) * 16 + lr];
        #pragma unroll
        for (int mt = 0; mt < 3; ++mt) {
            const int q = (mbase + mt) * 4 + lg;
            #pragma unroll
            for (int oct = 0; oct < 4; ++oct) {
                float s = 0.f;
                #pragma unroll
                for (int r4 = 0; r4 < 4; ++r4)
                    s += fmaxf(acc2[mt][oct][r4] + b2v[oct], 0.f);
                s *= 0.25f;
                const int idx = ((nbase + oct) * 16 + lr) * 24 + q;
                const f32x4* fp = (const f32x4*)(fc7 + idx * 8);
                const f32x4 f0 = fp[0], f1 = fp[1];
                dot[0] += s * f0[0]; dot[1] += s * f0[1];
                dot[2] += s * f0[2]; dot[3] += s * f0[3];
                dot[4] += s * f1[0]; dot[5] += s * f1[1];
                dot[6] += s * f1[2];
            }
        }
    }

    #pragma unroll
    for (int j = 0; j < 7; ++j) {
        float s = dot[j];
        #pragma unroll
        for (int off = 32; off; off >>= 1) s += __shfl_down(s, off);
        if (lane == 0) red[w * 8 + j] = s;
    }
    __syncthreads();
    if (t < 7) {
        float s = red[t] + red[8 + t] + red[16 + t] + red[24 + t];
        s += (t < 6) ? fc_b[t] : taubp[0];
        params[(size_t)b * 8 + t] = s;
    }
}

// ---------------------------------------------------------------------------
// Kernel 2: DMP rollout — 1 thread per batch element.
// ---------------------------------------------------------------------------
__global__ void rollout_kernel(const float* __restrict__ params,
                               const float* __restrict__ y0,
                               float* __restrict__ out) {
    const int b = blockIdx.x * 64 + threadIdx.x;
    const float* p = params + (size_t)b * 8;
    const float goal = p[0];
    const float w0 = p[1], w1 = p[2], w2 = p[3], w3 = p[4], w4 = p[5];
    const float tau = p[6];
    const float y0v = y0[b];

    const float c0 = 1.0f;
    const float c1 = 0.77880078307140486825f;
    const float c2 = 0.60653065971263342360f;
    const float c3 = 0.47236655274101470714f;
    const float c4 = 0.36787944117144232160f;
    const float inv2s = -0.5f / 11.180339887498949f;
    const float e0 = inv2s * c0, e1 = inv2s * c1, e2 = inv2s * c2,
                e3 = inv2s * c3, e4 = inv2s * c4;

    float x = 1.0f, y = y0v, z = 0.01f * tau;
    const float td = tau * 0.01f;
    const float gmy0 = goal - y0v;
    float* ob = out + (size_t)b * 101;
    ob[0] = y0v;
    for (int s = 1; s <= 100; ++s) {
        x = x - x * td;
        const float d0 = x - c0, d1 = x - c1, d2 = x - c2, d3 = x - c3, d4 = x - c4;
        const float p0 = __expf(e0 * d0 * d0);
        const float p1 = __expf(e1 * d1 * d1);
        const float p2 = __expf(e2 * d2 * d2);
        const float p3 = __expf(e3 * d3 * d3);
        const float p4 = __expf(e4 * d4 * d4);
        const float den = p0 + p1 + p2 + p3 + p4;
        const float num = w0 * p0 + w1 * p1 + w2 * p2 + w3 * p3 + w4 * p4;
        const float fx = (num / den) * x * gmy0;
        const float dz = 25.0f * (6.25f * (goal - y) - z) + fx;
        const float dy = z;
        y += dy * td;
        z += dz * td;
        ob[s] = y;
    }
}

extern "C" void kernel_launch(void* const* d_in, const int* in_sizes, int n_in,
                              void* d_out, int out_size, void* d_ws, size_t ws_size,
                              hipStream_t stream) {
    const float* input = (const float*)d_in[0];
    const float* y0    = (const float*)d_in[1];
    const float* w1    = (const float*)d_in[2];
    const float* b1    = (const float*)d_in[3];
    const float* w2    = (const float*)d_in[4];
    const float* b2    = (const float*)d_in[5];
    const float* fc_w  = (const float*)d_in[6];
    const float* fc_b  = (const float*)d_in[7];
    const float* L_w   = (const float*)d_in[8];
    const float* L_b   = (const float*)d_in[9];
    float* out = (float*)d_out;

    float* ws      = (float*)d_ws;
    float* fc7     = ws;                          // 24576 f
    float* taub    = ws + 24576;                  // pad to 64
    float* params  = ws + 24640;                  // 32768 f
    unsigned* wfrag1 = (unsigned*)(ws + 57408);   // 4096 u32
    unsigned* wfrag2 = wfrag1 + 4096;             // 40960 u32

    const int B = in_sizes[1];                    // 4096

    precompute_kernel<<<33, 256, 0, stream>>>(w1, w2, fc_w, fc_b, L_w, L_b,
                                              fc7, taub, wfrag1, wfrag2);
    fused_kernel<<<B, 256, 0, stream>>>(input, b1, b2, wfrag1, wfrag2,
                                        fc7, fc_b, taub, params);
    rollout_kernel<<<B / 64, 64, 0, stream>>>(params, y0, out);
}

// Round 4
// 178.859 us; speedup vs baseline: 3.6407x; 1.0102x over previous
//
#include <hip/hip_runtime.h>
#include <math.h>

// ---------------------------------------------------------------------------
// B=4096. conv1 (64,5,7) pad3 + relu + pool4 -> h1 (64,96)
//         conv2 (128,64,5) pad2 + relu + pool4 -> feat (128,24)
//         fc: only cols 0..5 of (404,3072) + tau = feat·(L_w@fc_w) + const.
// Split-bf16 MFMA (hi+lo, 3 mfma/product). conv2 = 5 shifted GEMMs (tap dk)
// over K=64(ic). G=2 batches per block: weight fragments loaded once per
// wave feed both batches (halves per-CU L2 weight traffic).
// C/D layout (m89): col=lane&15 -> oc, row=(lane>>4)*4+reg -> pos.
// ---------------------------------------------------------------------------

typedef short bf16x8 __attribute__((ext_vector_type(8)));
typedef float f32x4  __attribute__((ext_vector_type(4)));
typedef int   i32x4  __attribute__((ext_vector_type(4)));

union Frag { int u[4]; i32x4 q; bf16x8 v; };

__device__ __forceinline__ unsigned bf16_rne(float f) {
    unsigned u = __float_as_uint(f);
    return (u + 0x7fffu + ((u >> 16) & 1u)) >> 16;
}
__device__ __forceinline__ unsigned packsplit(float f) {
    unsigned hi = bf16_rne(f);
    float lo = f - __uint_as_float(hi << 16);
    return (hi << 16) | bf16_rne(lo);
}

// ---------------------------------------------------------------------------
// Kernel 0a: fc7 table. 12 blocks x 1024 threads; j-loop split 4 ways.
// fc7[k][0..5]=fc_w[j][k], [6]=(L_w@fc_w)[k], [7]=0
// ---------------------------------------------------------------------------
__global__ void precompute_fc(const float* __restrict__ fc_w,
                              const float* __restrict__ L_w,
                              float* __restrict__ fc7) {
    __shared__ float part[3][256];
    const int t = threadIdx.x, k = blockIdx.x * 256 + (t & 255), jc = t >> 8;
    const int j0 = jc * 101;
    float s = 0.f;
    #pragma unroll 4
    for (int j = j0; j < j0 + 101; ++j) s += L_w[j] * fc_w[j * 3072 + k];
    if (jc) part[jc - 1][t & 255] = s;
    __syncthreads();
    if (jc == 0) {
        const int kk = t & 255;
        float r[8];
        #pragma unroll
        for (int j = 0; j < 6; ++j) r[j] = fc_w[j * 3072 + k];
        r[6] = s + part[0][kk] + part[1][kk] + part[2][kk];
        r[7] = 0.f;
        #pragma unroll
        for (int j = 0; j < 8; ++j) fc7[k * 8 + j] = r[j];
    }
}

// ---------------------------------------------------------------------------
// Kernel 0b: taub + weight-fragment tables (hi/lo). 21 blocks x 256.
//  wfrag1: [split2][ks2][oct4][lane64][4u32]       (conv1, K'=64 padded)
//  wfrag2: [split2][dk5][ks2][oct8][lane64][4u32]  (conv2 taps, K=64=ic)
// ---------------------------------------------------------------------------
__global__ void precompute_frags(const float* __restrict__ w1,
                                 const float* __restrict__ w2,
                                 const float* __restrict__ fc_b,
                                 const float* __restrict__ L_w,
                                 const float* __restrict__ L_b,
                                 float* __restrict__ taub,
                                 unsigned* __restrict__ wfrag1,
                                 unsigned* __restrict__ wfrag2) {
    const int t = threadIdx.x, bb = blockIdx.x;
    if (bb == 0) {
        if (t < 64) {
            float s = 0.f;
            for (int j = t; j < 404; j += 64) s += L_w[j] * fc_b[j];
            #pragma unroll
            for (int off = 32; off; off >>= 1) s += __shfl_down(s, off);
            if (t == 0) taub[0] = s + L_b[0];
        }
        for (int it = t; it < 1024; it += 256) {    // conv1 frags
            const int split = it >> 9, ks = (it >> 8) & 1,
                      oct = (it >> 6) & 3, lane = it & 63;
            const int oc = oct * 16 + (lane & 15);
            unsigned h[8];
            #pragma unroll
            for (int j = 0; j < 8; ++j) {
                const int kp = ks * 32 + (lane >> 4) * 8 + j;  // k' = dk*8+ic
                const int dk = kp >> 3, ic = kp & 7;
                float v = (ic < 5 && dk < 7) ? w1[oc * 35 + ic * 7 + dk] : 0.f;
                unsigned hb = bf16_rne(v);
                if (split) hb = bf16_rne(v - __uint_as_float(hb << 16));
                h[j] = hb;
            }
            #pragma unroll
            for (int wj = 0; wj < 4; ++wj)
                wfrag1[it * 4 + wj] = (h[2 * wj + 1] << 16) | h[2 * wj];
        }
    } else {                                        // conv2 tap frags: 10240
        const int base = (bb - 1) * 512;
        #pragma unroll
        for (int r = 0; r < 2; ++r) {
            const int it = base + r * 256 + t;
            const int split = it / 5120, rem = it % 5120;
            const int dk = rem >> 10, rem2 = rem & 1023;
            const int ks = rem2 >> 9, oct = (rem2 >> 6) & 7, lane = rem2 & 63;
            const int oc = oct * 16 + (lane & 15);
            unsigned h[8];
            #pragma unroll
            for (int j = 0; j < 8; ++j) {
                const int ic = ks * 32 + (lane >> 4) * 8 + j;   // k = ic
                const float v = w2[oc * 320 + ic * 5 + dk];
                unsigned hb = bf16_rne(v);
                if (split) hb = bf16_rne(v - __uint_as_float(hb << 16));
                h[j] = hb;
            }
            #pragma unroll
            for (int wj = 0; wj < 4; ++wj)
                wfrag2[it * 4 + wj] = (h[2 * wj + 1] << 16) | h[2 * wj];
        }
    }
}

// ---------------------------------------------------------------------------
// Kernel 1: fused conv1+conv2+fc for TWO batches per block.
// LDS (76672 B):
//  [0,18816)      lds_in  u32[2][6][392]  (row5 = zeros for j-clamp)
//  [18816,47616)  h1t_hi  bf16[2][100][72] (rows 0,1,98,99 halo-zero)
//  [47616,76416)  h1t_lo  bf16[2][100][72]
//  [76416,76672)  red     f32[64]
// ---------------------------------------------------------------------------
__global__ __launch_bounds__(256, 2) void fused_kernel(
    const float* __restrict__ input,
    const float* __restrict__ b1,
    const float* __restrict__ b2,
    const unsigned* __restrict__ wfrag1,
    const unsigned* __restrict__ wfrag2,
    const float* __restrict__ fc7,
    const float* __restrict__ fc_b,
    const float* __restrict__ taubp,
    float* __restrict__ params)
{
    __shared__ __align__(16) unsigned char smem[76672];
    unsigned* lds_in = (unsigned*)smem;                       // [2][2352]
    unsigned short* h1t_hi = (unsigned short*)(smem + 18816); // [2][7200]
    unsigned short* h1t_lo = (unsigned short*)(smem + 47616);
    unsigned* h1t32 = (unsigned*)(smem + 18816);              // both arrays
    float* red = (float*)(smem + 76416);

    const int t = threadIdx.x, b0 = blockIdx.x * 2;
    const int lane = t & 63, w = t >> 6;
    const int lg = lane >> 4, lr = lane & 15;

    // ---- zero lds_in + h1t halo rows ----
    for (int i = t; i < 4704; i += 256) lds_in[i] = 0u;
    for (int i = t; i < 576; i += 256) {
        const int wd = i % 36, r = (i / 36) & 3, a = (i / 144) & 1, g = i / 288;
        const int row = (r < 2) ? r : 96 + r;                 // 0,1,98,99
        h1t32[a * 7200 + g * 3600 + row * 36 + wd] = 0u;
    }
    __syncthreads();
    // ---- stage both batches' input as packed hi|lo bf16 ----
    for (int i = t; i < 3840; i += 256) {
        const int g = i / 1920, r = i - g * 1920;
        const int ic = r / 384, x = r - ic * 384;
        lds_in[g * 2352 + ic * 392 + 3 + x] =
            packsplit(input[(size_t)(b0 + g) * 1920 + r]);
    }
    __syncthreads();

    // ---------------- conv1: C[pos=384][oc=64], K'=64, both batches --------
    const i32x4* w1f = (const i32x4*)wfrag1;
    Frag c1bh[2][4], c1bl[2][4];
    #pragma unroll
    for (int ks = 0; ks < 2; ++ks)
        #pragma unroll
        for (int oct = 0; oct < 4; ++oct) {
            c1bh[ks][oct].q = w1f[(ks * 4 + oct) * 64 + lane];
            c1bl[ks][oct].q = w1f[((2 + ks) * 4 + oct) * 64 + lane];
        }
    float b1v[4];
    #pragma unroll
    for (int oct = 0; oct < 4; ++oct) b1v[oct] = b1[oct * 16 + lr];

    #pragma unroll
    for (int g = 0; g < 2; ++g) {
        const unsigned* aB1 = lds_in + g * 2352 + w * 96 + lr + lg;
        #pragma unroll
        for (int mt = 0; mt < 6; ++mt) {
            f32x4 acc[4];
            #pragma unroll
            for (int oct = 0; oct < 4; ++oct) acc[oct] = (f32x4){0.f, 0.f, 0.f, 0.f};
            #pragma unroll
            for (int ks = 0; ks < 2; ++ks) {
                unsigned p[8];
                #pragma unroll
                for (int j = 0; j < 8; ++j) {
                    const int jr = (j < 5) ? j : 5;           // row5 = zeros
                    p[j] = aB1[mt * 16 + ks * 4 + jr * 392];
                }
                Frag ah, al;
                #pragma unroll
                for (int wj = 0; wj < 4; ++wj) {
                    ah.u[wj] = __builtin_amdgcn_perm(p[2*wj+1], p[2*wj], 0x07060302u);
                    al.u[wj] = __builtin_amdgcn_perm(p[2*wj+1], p[2*wj], 0x05040100u);
                }
                #pragma unroll
                for (int oct = 0; oct < 4; ++oct)
                    acc[oct] = __builtin_amdgcn_mfma_f32_16x16x32_bf16(ah.v, c1bh[ks][oct].v, acc[oct], 0, 0, 0);
                #pragma unroll
                for (int oct = 0; oct < 4; ++oct)
                    acc[oct] = __builtin_amdgcn_mfma_f32_16x16x32_bf16(ah.v, c1bl[ks][oct].v, acc[oct], 0, 0, 0);
                #pragma unroll
                for (int oct = 0; oct < 4; ++oct)
                    acc[oct] = __builtin_amdgcn_mfma_f32_16x16x32_bf16(al.v, c1bh[ks][oct].v, acc[oct], 0, 0, 0);
            }
            const int c = (w * 6 + mt) * 4 + lg;
            #pragma unroll
            for (int oct = 0; oct < 4; ++oct) {
                float s = 0.f;
                #pragma unroll
                for (int r4 = 0; r4 < 4; ++r4) s += fmaxf(acc[oct][r4] + b1v[oct], 0.f);
                const float v = 0.25f * s;
                const unsigned hi = bf16_rne(v);
                const unsigned lo = bf16_rne(v - __uint_as_float(hi << 16));
                const int idx = g * 7200 + (c + 2) * 72 + oct * 16 + lr;
                h1t_hi[idx] = (unsigned short)hi;
                h1t_lo[idx] = (unsigned short)lo;
            }
        }
    }
    __syncthreads();

    // -------- conv2: 5 taps x K=64, C[pos=96][oc=128], both batches --------
    const int mbase = (w & 1) * 3, nbase = (w >> 1) * 4;
    f32x4 acc2[2][3][4];
    #pragma unroll
    for (int g = 0; g < 2; ++g)
        #pragma unroll
        for (int mt = 0; mt < 3; ++mt)
            #pragma unroll
            for (int oct = 0; oct < 4; ++oct)
                acc2[g][mt][oct] = (f32x4){0.f, 0.f, 0.f, 0.f};

    const i32x4* aHi[2], *aLo[2];
    #pragma unroll
    for (int g = 0; g < 2; ++g) {
        aHi[g] = (const i32x4*)(h1t_hi + g * 7200 + (mbase * 16 + lr) * 72 + lg * 8);
        aLo[g] = (const i32x4*)(h1t_lo + g * 7200 + (mbase * 16 + lr) * 72 + lg * 8);
    }
    const i32x4* w2f = (const i32x4*)wfrag2;
    #pragma unroll
    for (int dk = 0; dk < 5; ++dk) {
        #pragma unroll
        for (int ks = 0; ks < 2; ++ks) {
            Frag bh[4], bl[4];
            #pragma unroll
            for (int oct = 0; oct < 4; ++oct) {
                bh[oct].q = w2f[((dk * 2 + ks) * 8 + nbase + oct) * 64 + lane];
                bl[oct].q = w2f[(((5 + dk) * 2 + ks) * 8 + nbase + oct) * 64 + lane];
            }
            #pragma unroll
            for (int g = 0; g < 2; ++g) {
                #pragma unroll
                for (int mt = 0; mt < 3; ++mt) {
                    Frag ah, al;
                    ah.q = aHi[g][mt * 144 + dk * 9 + ks * 4];
                    al.q = aLo[g][mt * 144 + dk * 9 + ks * 4];
                    #pragma unroll
                    for (int oct = 0; oct < 4; ++oct)
                        acc2[g][mt][oct] = __builtin_amdgcn_mfma_f32_16x16x32_bf16(ah.v, bh[oct].v, acc2[g][mt][oct], 0, 0, 0);
                    #pragma unroll
                    for (int oct = 0; oct < 4; ++oct)
                        acc2[g][mt][oct] = __builtin_amdgcn_mfma_f32_16x16x32_bf16(ah.v, bl[oct].v, acc2[g][mt][oct], 0, 0, 0);
                    #pragma unroll
                    for (int oct = 0; oct < 4; ++oct)
                        acc2[g][mt][oct] = __builtin_amdgcn_mfma_f32_16x16x32_bf16(al.v, bh[oct].v, acc2[g][mt][oct], 0, 0, 0);
                }
            }
        }
    }

    // ---- epilogue per batch: bias+relu+pool4 + fc7 dots + reduce ----
    float b2v[4];
    #pragma unroll
    for (int oct = 0; oct < 4; ++oct) b2v[oct] = b2[(nbase + oct) * 16 + lr];
    #pragma unroll
    for (int g = 0; g < 2; ++g) {
        float dot[7] = {0.f, 0.f, 0.f, 0.f, 0.f, 0.f, 0.f};
        #pragma unroll
        for (int mt = 0; mt < 3; ++mt) {
            const int q = (mbase + mt) * 4 + lg;
            #pragma unroll
            for (int oct = 0; oct < 4; ++oct) {
                float s = 0.f;
                #pragma unroll
                for (int r4 = 0; r4 < 4; ++r4)
                    s += fmaxf(acc2[g][mt][oct][r4] + b2v[oct], 0.f);
                s *= 0.25f;
                const int idx = ((nbase + oct) * 16 + lr) * 24 + q;
                const f32x4* fp = (const f32x4*)(fc7 + idx * 8);
                const f32x4 f0 = fp[0], f1 = fp[1];
                dot[0] += s * f0[0]; dot[1] += s * f0[1];
                dot[2] += s * f0[2]; dot[3] += s * f0[3];
                dot[4] += s * f1[0]; dot[5] += s * f1[1];
                dot[6] += s * f1[2];
            }
        }
        #pragma unroll
        for (int j = 0; j < 7; ++j) {
            float s = dot[j];
            #pragma unroll
            for (int off = 32; off; off >>= 1) s += __shfl_down(s, off);
            if (lane == 0) red[g * 32 + w * 8 + j] = s;
        }
    }
    __syncthreads();
    if (t < 7) {
        float s = red[t] + red[8 + t] + red[16 + t] + red[24 + t];
        s += (t < 6) ? fc_b[t] : taubp[0];
        params[(size_t)b0 * 8 + t] = s;
    } else if (t >= 64 && t < 71) {
        const int j = t - 64;
        float s = red[32 + j] + red[40 + j] + red[48 + j] + red[56 + j];
        s += (j < 6) ? fc_b[j] : taubp[0];
        params[(size_t)(b0 + 1) * 8 + j] = s;
    }
}

// ---------------------------------------------------------------------------
// Kernel 2: DMP rollout — 1 thread per batch element.
// ---------------------------------------------------------------------------
__global__ void rollout_kernel(const float* __restrict__ params,
                               const float* __restrict__ y0,
                               float* __restrict__ out) {
    const int b = blockIdx.x * 256 + threadIdx.x;
    const float* p = params + (size_t)b * 8;
    const float goal = p[0];
    const float w0 = p[1], w1 = p[2], w2 = p[3], w3 = p[4], w4 = p[5];
    const float tau = p[6];
    const float y0v = y0[b];

    const float c0 = 1.0f;
    const float c1 = 0.77880078307140486825f;
    const float c2 = 0.60653065971263342360f;
    const float c3 = 0.47236655274101470714f;
    const float c4 = 0.36787944117144232160f;
    const float inv2s = -0.5f / 11.180339887498949f;
    const float e0 = inv2s * c0, e1 = inv2s * c1, e2 = inv2s * c2,
                e3 = inv2s * c3, e4 = inv2s * c4;

    float x = 1.0f, y = y0v, z = 0.01f * tau;
    const float td = tau * 0.01f;
    const float gmy0 = goal - y0v;
    float* ob = out + (size_t)b * 101;
    ob[0] = y0v;
    for (int s = 1; s <= 100; ++s) {
        x = x - x * td;
        const float d0 = x - c0, d1 = x - c1, d2 = x - c2, d3 = x - c3, d4 = x - c4;
        const float p0 = __expf(e0 * d0 * d0);
        const float p1 = __expf(e1 * d1 * d1);
        const float p2 = __expf(e2 * d2 * d2);
        const float p3 = __expf(e3 * d3 * d3);
        const float p4 = __expf(e4 * d4 * d4);
        const float den = p0 + p1 + p2 + p3 + p4;
        const float num = w0 * p0 + w1 * p1 + w2 * p2 + w3 * p3 + w4 * p4;
        const float fx = (num / den) * x * gmy0;
        const float dz = 25.0f * (6.25f * (goal - y) - z) + fx;
        const float dy = z;
        y += dy * td;
        z += dz * td;
        ob[s] = y;
    }
}

extern "C" void kernel_launch(void* const* d_in, const int* in_sizes, int n_in,
                              void* d_out, int out_size, void* d_ws, size_t ws_size,
                              hipStream_t stream) {
    const float* input = (const float*)d_in[0];
    const float* y0    = (const float*)d_in[1];
    const float* w1    = (const float*)d_in[2];
    const float* b1    = (const float*)d_in[3];
    const float* w2    = (const float*)d_in[4];
    const float* b2    = (const float*)d_in[5];
    const float* fc_w  = (const float*)d_in[6];
    const float* fc_b  = (const float*)d_in[7];
    const float* L_w   = (const float*)d_in[8];
    const float* L_b   = (const float*)d_in[9];
    float* out = (float*)d_out;

    float* ws      = (float*)d_ws;
    float* fc7     = ws;                          // 24576 f
    float* taub    = ws + 24576;                  // pad to 64
    float* params  = ws + 24640;                  // 32768 f
    unsigned* wfrag1 = (unsigned*)(ws + 57408);   // 4096 u32
    unsigned* wfrag2 = wfrag1 + 4096;             // 40960 u32

    const int B = in_sizes[1];                    // 4096

    precompute_fc<<<12, 1024, 0, stream>>>(fc_w, L_w, fc7);
    precompute_frags<<<21, 256, 0, stream>>>(w1, w2, fc_b, L_w, L_b,
                                             taub, wfrag1, wfrag2);
    fused_kernel<<<B / 2, 256, 0, stream>>>(input, b1, b2, wfrag1, wfrag2,
                                            fc7, fc_b, taub, params);
    rollout_kernel<<<B / 256, 256, 0, stream>>>(params, y0, out);
}